// Round 9
// baseline (315.259 us; speedup 1.0000x reference)
//
#include <hip/hip_runtime.h>
#include <hip/hip_bf16.h>

#define NT 64
#define DIM 128

typedef __attribute__((ext_vector_type(8))) short short8;
typedef __attribute__((ext_vector_type(4))) short short4v;
typedef __attribute__((ext_vector_type(8))) __bf16 bf16x8;
typedef __attribute__((ext_vector_type(4))) float floatx4;
typedef __attribute__((ext_vector_type(4))) unsigned uintx4;

#define MFMA(a,b,c) __builtin_amdgcn_mfma_f32_16x16x32_bf16(a,b,c,0,0,0)
#define SWZ(idx, row) ((idx) ^ (((row)&7)<<3))

__device__ __forceinline__ short bfbits(float f) {
  return __builtin_bit_cast(short, (__bf16)f);
}
__device__ __forceinline__ unsigned pk2(float lo, float hi) {
  return (unsigned)(unsigned short)__builtin_bit_cast(unsigned short, (__bf16)lo)
       | ((unsigned)(unsigned short)__builtin_bit_cast(unsigned short, (__bf16)hi) << 16);
}
__device__ __forceinline__ bf16x8 frag_bf(const short* __restrict__ p) {
  return __builtin_bit_cast(bf16x8, *(const short8*)p);
}
__device__ __forceinline__ short8 pack8(float4 a, float4 b) {
  short8 v;
  v[0]=bfbits(a.x); v[1]=bfbits(a.y); v[2]=bfbits(a.z); v[3]=bfbits(a.w);
  v[4]=bfbits(b.x); v[5]=bfbits(b.y); v[6]=bfbits(b.z); v[7]=bfbits(b.w);
  return v;
}

// ---------------- prep: CPB MLP + bias packing (S^T order) + weight bf16 ----
__global__ void prep_kernel(const float* __restrict__ table,
                            const float* __restrict__ w1,
                            const float* __restrict__ b1,
                            const float* __restrict__ w2,
                            const int*   __restrict__ idx,
                            const float* __restrict__ q_w,
                            const float* __restrict__ kv_w,
                            const float* __restrict__ proj_w,
                            float* __restrict__ bias_packed,
                            short* __restrict__ wbf) {
  int t = threadIdx.x;
  if (blockIdx.x == 0) {
    __shared__ float logits[225][4];
    if (t < 225) {
      float t0 = table[2*t], t1 = table[2*t+1];
      float a0=0.f, a1=0.f, a2=0.f, a3=0.f;
      for (int j = 0; j < 512; ++j) {
        float h = fmaxf(0.f, t0 * w1[2*j] + t1 * w1[2*j+1] + b1[j]);
        a0 += h * w2[j];
        a1 += h * w2[512 + j];
        a2 += h * w2[1024 + j];
        a3 += h * w2[1536 + j];
      }
      logits[t][0]=a0; logits[t][1]=a1; logits[t][2]=a2; logits[t][3]=a3;
    }
    __syncthreads();
    for (int f = t; f < 16384; f += 256) {
      int i    = f & 3;
      int lane = (f >> 2) & 63;
      int qt   = (f >> 8) & 3;
      int mk   = (f >> 10) & 3;
      int h    = f >> 12;
      int q = qt*16 + (lane & 15);
      int k = mk*16 + ((lane >> 4) & 3)*4 + i;
      int p = idx[q*64 + k];
      float v = logits[p][h];
      bias_packed[f] = 16.f / (1.f + __expf(-v));
    }
  } else {
    int gidx = (blockIdx.x - 1) * 4096 + t * 16;
    const float* src; int off;
    if (gidx < 16384)      { src = q_w;    off = gidx; }
    else if (gidx < 49152) { src = kv_w;   off = gidx - 16384; }
    else                   { src = proj_w; off = gidx - 49152; }
    const float4* s = (const float4*)(src + off);
    short* dst = wbf + gidx;
#pragma unroll
    for (int i = 0; i < 2; ++i)
      *(short8*)(dst + i*8) = pack8(s[2*i], s[2*i+1]);
  }
}

// ---------------- K1: QKV projection (streaming GEMM, 1 barrier) ----------
// wave == head. Writes per (win,head): Qn [64tok][32ch] (l2norm * scl),
// Kn [64tok][32ch] (l2norm), V^T [32ch][64tok] (+v_b). All bf16, packed short4.
// Q^T,K^T via swapped mfma(W,X) -> 2-shfl norm + row-packed writes.
__global__ __launch_bounds__(256, 5)
void qkv_kernel(const float* __restrict__ x, const float* __restrict__ ctx,
                const short* __restrict__ wq, const float* __restrict__ q_b,
                const short* __restrict__ wkv, const float* __restrict__ v_b,
                const float* __restrict__ logit_scale,
                short* __restrict__ qn, short* __restrict__ kn,
                short* __restrict__ vt) {
  __shared__ short lds[16384] __attribute__((aligned(16)));  // 32 KB
  const int tid  = threadIdx.x;
  const int lane = tid & 63;
  const int h    = tid >> 6;
  const int b    = blockIdx.x;
  const int lr   = lane & 15;
  const int lg   = lane >> 4;

  short* xb = lds;          // [64][128] swz
  short* cb = lds + 8192;   // [64][128] swz

  // ---- stage x + ctx ----
  {
    const int sr = tid >> 2, c0 = (tid & 3) * 32;
    const float4* xs = (const float4*)(x   + (size_t)b*(NT*DIM) + sr*DIM + c0);
    const float4* cs = (const float4*)(ctx + (size_t)b*(NT*DIM) + sr*DIM + c0);
    float4 xr[8], cr[8];
#pragma unroll
    for (int i = 0; i < 8; ++i) xr[i] = xs[i];
#pragma unroll
    for (int i = 0; i < 8; ++i) cr[i] = cs[i];
#pragma unroll
    for (int j = 0; j < 4; ++j)
      *(short8*)(xb + SWZ(sr*128 + c0 + j*8, sr)) = pack8(xr[2*j], xr[2*j+1]);
#pragma unroll
    for (int j = 0; j < 4; ++j)
      *(short8*)(cb + SWZ(sr*128 + c0 + j*8, sr)) = pack8(cr[2*j], cr[2*j+1]);
  }
  __syncthreads();  // only barrier

  const float scl = __expf(fminf(logit_scale[h], 4.605170185988091f));  // log(100)
  const size_t wh = ((size_t)b*4 + h) * 2048;   // 64*32 elems per (win,head)

  // ---- Q^T = mfma(Wq, X) ; +q_b ; l2norm*scl ; packed row writes ----
  {
    floatx4 aq[2][4] = {};
    for (int ks = 0; ks < 4; ++ks) {
      bf16x8 Bx[4], Aw[2];
#pragma unroll
      for (int nt = 0; nt < 4; ++nt) {
        int tok = nt*16 + lr;
        Bx[nt] = frag_bf(xb + SWZ(tok*128 + ks*32 + lg*8, tok));
      }
#pragma unroll
      for (int mc = 0; mc < 2; ++mc)
        Aw[mc] = frag_bf(wq + (h*32 + mc*16 + lr)*DIM + ks*32 + lg*8);
#pragma unroll
      for (int mc = 0; mc < 2; ++mc)
#pragma unroll
        for (int nt = 0; nt < 4; ++nt)
          aq[mc][nt] = MFMA(Aw[mc], Bx[nt], aq[mc][nt]);
    }
    floatx4 qb4[2];
#pragma unroll
    for (int mc = 0; mc < 2; ++mc)
      qb4[mc] = *(const floatx4*)(q_b + h*32 + mc*16 + lg*4);
#pragma unroll
    for (int nt = 0; nt < 4; ++nt) {
      float ss = 0.f;
#pragma unroll
      for (int mc = 0; mc < 2; ++mc)
#pragma unroll
        for (int i = 0; i < 4; ++i) {
          aq[mc][nt][i] += qb4[mc][i];
          ss += aq[mc][nt][i]*aq[mc][nt][i];
        }
      ss += __shfl_xor(ss, 16, 64);
      ss += __shfl_xor(ss, 32, 64);
      float sc = scl / fmaxf(sqrtf(ss), 1e-12f);
      int tok = nt*16 + lr;
#pragma unroll
      for (int mc = 0; mc < 2; ++mc) {
        short4v t4;
#pragma unroll
        for (int i = 0; i < 4; ++i) t4[i] = bfbits(aq[mc][nt][i] * sc);
        *(short4v*)(qn + wh + tok*32 + mc*16 + lg*4) = t4;
      }
    }
  }

  // ---- K^T = mfma(Wk, Ctx) ; l2norm ; packed row writes ----
  {
    floatx4 ak[2][4] = {};
    for (int ks = 0; ks < 4; ++ks) {
      bf16x8 Bx[4], Aw[2];
#pragma unroll
      for (int nt = 0; nt < 4; ++nt) {
        int tok = nt*16 + lr;
        Bx[nt] = frag_bf(cb + SWZ(tok*128 + ks*32 + lg*8, tok));
      }
#pragma unroll
      for (int mc = 0; mc < 2; ++mc)
        Aw[mc] = frag_bf(wkv + (h*32 + mc*16 + lr)*DIM + ks*32 + lg*8);
#pragma unroll
      for (int mc = 0; mc < 2; ++mc)
#pragma unroll
        for (int nt = 0; nt < 4; ++nt)
          ak[mc][nt] = MFMA(Aw[mc], Bx[nt], ak[mc][nt]);
    }
#pragma unroll
    for (int nt = 0; nt < 4; ++nt) {
      float ss = 0.f;
#pragma unroll
      for (int mc = 0; mc < 2; ++mc)
#pragma unroll
        for (int i = 0; i < 4; ++i) ss += ak[mc][nt][i]*ak[mc][nt][i];
      ss += __shfl_xor(ss, 16, 64);
      ss += __shfl_xor(ss, 32, 64);
      float sc = 1.0f / fmaxf(sqrtf(ss), 1e-12f);
      int tok = nt*16 + lr;
#pragma unroll
      for (int mc = 0; mc < 2; ++mc) {
        short4v t4;
#pragma unroll
        for (int i = 0; i < 4; ++i) t4[i] = bfbits(ak[mc][nt][i] * sc);
        *(short4v*)(kn + wh + tok*32 + mc*16 + lg*4) = t4;
      }
    }
  }

  // ---- V = mfma(Ctx, Wv) ; +v_b ; V^T packed writes ----
  {
    floatx4 av[4][2] = {};
    for (int ks = 0; ks < 4; ++ks) {
      bf16x8 A[4], W[2];
#pragma unroll
      for (int mt = 0; mt < 4; ++mt) {
        int tok = mt*16 + lr;
        A[mt] = frag_bf(cb + SWZ(tok*128 + ks*32 + lg*8, tok));
      }
#pragma unroll
      for (int n = 0; n < 2; ++n)
        W[n] = frag_bf(wkv + (DIM + h*32 + n*16 + lr)*DIM + ks*32 + lg*8);
#pragma unroll
      for (int n = 0; n < 2; ++n)
#pragma unroll
        for (int mt = 0; mt < 4; ++mt)
          av[mt][n] = MFMA(A[mt], W[n], av[mt][n]);
    }
    float vb0 = v_b[h*32 + lr], vb1 = v_b[h*32 + 16 + lr];
#pragma unroll
    for (int mt = 0; mt < 4; ++mt)
#pragma unroll
      for (int n = 0; n < 2; ++n) {
        float vb = n ? vb1 : vb0;
        short4v t4;
#pragma unroll
        for (int i = 0; i < 4; ++i) t4[i] = bfbits(av[mt][n][i] + vb);
        *(short4v*)(vt + wh + (n*16 + lr)*64 + mt*16 + lg*4) = t4;
      }
  }
}

// ---------------- K2: attention + proj (1 barrier) -------------------------
// wave == (window, head), fully independent until proj barrier.
// S^T = mfma(Kn,Qn) -> lane-local softmax; pB perm-dance; O^T frags ->
// packed [tok][ch] LDS; proj GEMM -> out.
__global__ __launch_bounds__(256, 4)
void attn_proj_kernel(const short* __restrict__ qn, const short* __restrict__ kn,
                      const short* __restrict__ vt,
                      const float* __restrict__ mask,
                      const short* __restrict__ wproj, const float* __restrict__ proj_b,
                      const float* __restrict__ bias_p,
                      float* __restrict__ out) {
  __shared__ short outp[8192] __attribute__((aligned(16)));  // [64][128] swz, 16 KB
  const int tid  = threadIdx.x;
  const int lane = tid & 63;
  const int h    = tid >> 6;
  const int b    = blockIdx.x;
  const int lr   = lane & 15;
  const int lg   = lane >> 4;

  const size_t wh = ((size_t)b*4 + h) * 2048;
  const short* qh = qn + wh;
  const short* kh = kn + wh;
  const short* vh = vt + wh;

  // ---- S^T = mfma(Kn rows, Qn rows) : [ktok][qtok] ----
  floatx4 st[4][4] = {};
  {
    bf16x8 qf[4];
#pragma unroll
    for (int nq = 0; nq < 4; ++nq)
      qf[nq] = frag_bf(qh + (nq*16 + lr)*32 + lg*8);
#pragma unroll
    for (int mk = 0; mk < 4; ++mk) {
      bf16x8 kf = frag_bf(kh + (mk*16 + lr)*32 + lg*8);
#pragma unroll
      for (int nq = 0; nq < 4; ++nq)
        st[mk][nq] = MFMA(kf, qf[nq], st[mk][nq]);
    }
  }

  // ---- +bias +mask, softmax over k (local 16 + 2 shfl) ----
  float rinv[4];
  {
    int wimg = b & 63;
#pragma unroll
    for (int nq = 0; nq < 4; ++nq) {
      int qcol = nq*16 + lr;
#pragma unroll
      for (int mk = 0; mk < 4; ++mk) {
        floatx4 b4 = ((const floatx4*)bias_p)[((h*4 + mk)*4 + nq)*64 + lane];
        floatx4 m4 = *(const floatx4*)(mask + ((size_t)wimg*64 + qcol)*64 + mk*16 + lg*4);
#pragma unroll
        for (int i = 0; i < 4; ++i) st[mk][nq][i] += b4[i] + m4[i];
      }
      float mx = st[0][nq][0];
#pragma unroll
      for (int mk = 0; mk < 4; ++mk)
#pragma unroll
        for (int i = 0; i < 4; ++i) mx = fmaxf(mx, st[mk][nq][i]);
      mx = fmaxf(mx, __shfl_xor(mx, 16, 64));
      mx = fmaxf(mx, __shfl_xor(mx, 32, 64));
      float sum = 0.f;
#pragma unroll
      for (int mk = 0; mk < 4; ++mk)
#pragma unroll
        for (int i = 0; i < 4; ++i) {
          st[mk][nq][i] = __expf(st[mk][nq][i] - mx);
          sum += st[mk][nq][i];
        }
      sum += __shfl_xor(sum, 16, 64);
      sum += __shfl_xor(sum, 32, 64);
      rinv[nq] = 1.0f / sum;
    }
  }

  // ---- PV: build pB per (nq,kk) via perm-dance, O^T = mfma(V^T, pB) ----
  const int sA = ((lane & 16) << 1) | (lane & 15);
  const int sB = sA + 16;
  const unsigned selp = (lane & 32) ? 0x07060302u : 0x05040100u;
  floatx4 ot[2][4] = {};
#pragma unroll
  for (int nq = 0; nq < 4; ++nq) {
#pragma unroll
    for (int kk = 0; kk < 2; ++kk) {
      unsigned pp[4], w[8];
#pragma unroll
      for (int i = 0; i < 4; ++i) pp[i] = pk2(st[2*kk][nq][i], st[2*kk+1][nq][i]);
#pragma unroll
      for (int j = 0; j < 8; ++j) w[j] = __shfl(pp[j & 3], (j < 4) ? sA : sB, 64);
      uintx4 u;
#pragma unroll
      for (int t = 0; t < 4; ++t) u[t] = __builtin_amdgcn_perm(w[2*t+1], w[2*t], selp);
      bf16x8 pB = __builtin_bit_cast(bf16x8, u);
#pragma unroll
      for (int mo = 0; mo < 2; ++mo) {
        bf16x8 vf = frag_bf(vh + (mo*16 + lr)*64 + kk*32 + lg*8);
        ot[mo][nq] = MFMA(vf, pB, ot[mo][nq]);
      }
    }
  }

  // ---- O^T frags -> packed [tok][ch] rows in LDS (rescaled by 1/sum) ----
#pragma unroll
  for (int mo = 0; mo < 2; ++mo)
#pragma unroll
    for (int nq = 0; nq < 4; ++nq) {
      int tok = nq*16 + lr;
      short4v t4;
#pragma unroll
      for (int i = 0; i < 4; ++i) t4[i] = bfbits(ot[mo][nq][i] * rinv[nq]);
      *(short4v*)(outp + SWZ(tok*128 + h*32 + mo*16 + lg*4, tok)) = t4;
    }
  __syncthreads();  // only barrier

  // ---- out = outp @ proj_w.T + proj_b ----
  {
    floatx4 ap[4][2] = {};
    for (int ks = 0; ks < 4; ++ks) {
      bf16x8 of[4], wpf[2];
#pragma unroll
      for (int m = 0; m < 4; ++m) {
        int tok = m*16 + lr;
        of[m] = frag_bf(outp + SWZ(tok*128 + ks*32 + lg*8, tok));
      }
#pragma unroll
      for (int n = 0; n < 2; ++n)
        wpf[n] = frag_bf(wproj + (h*32 + n*16 + lr)*DIM + ks*32 + lg*8);
#pragma unroll
      for (int n = 0; n < 2; ++n)
#pragma unroll
        for (int m = 0; m < 4; ++m)
          ap[m][n] = MFMA(of[m], wpf[n], ap[m][n]);
    }
    float pb0 = proj_b[h*32 + lr], pb1 = proj_b[h*32 + 16 + lr];
    float* op = out + (size_t)b * (NT*DIM);
#pragma unroll
    for (int m = 0; m < 4; ++m)
#pragma unroll
      for (int n = 0; n < 2; ++n) {
        float pb = n ? pb1 : pb0;
#pragma unroll
        for (int i = 0; i < 4; ++i)
          op[(m*16 + lg*4 + i)*DIM + h*32 + n*16 + lr] = ap[m][n][i] + pb;
      }
  }
}

// ---------------- fallback: round-6 fused kernel (verified, ~242 us) -------
__global__ __launch_bounds__(512, 6)
void fused_fallback_kernel(const float* __restrict__ x, const float* __restrict__ ctx,
                           const float* __restrict__ mask,
                           const short* __restrict__ wq, const float* __restrict__ q_b,
                           const short* __restrict__ wkv, const float* __restrict__ v_b,
                           const float* __restrict__ logit_scale,
                           const short* __restrict__ wproj, const float* __restrict__ proj_b,
                           const float* __restrict__ bias_p,
                           float* __restrict__ out) {
  __shared__ short lds[24576] __attribute__((aligned(16)));
  const int tid  = threadIdx.x;
  const int lane = tid & 63;
  const int wv   = tid >> 6;
  const int h    = wv >> 1;
  const int s    = wv & 1;
  const int b    = blockIdx.x;
  const int lr   = lane & 15;
  const int lg   = lane >> 4;

  short* xb   = lds;
  short* cb   = lds + 8192;
  short* kn   = lds + 16384;
  short* vT   = xb;
  short* outp = cb;
  short* knh  = kn + h*2048;

  const float* xw = x   + (size_t)b*(NT*DIM);
  const float* cw = ctx + (size_t)b*(NT*DIM);

  {
    const int sr = tid >> 3, sc0 = (tid & 7) * 16;
    const float4* xs = (const float4*)(xw + sr*DIM + sc0);
    const float4* cs = (const float4*)(cw + sr*DIM + sc0);
    float4 xr[4], cr[4];
#pragma unroll
    for (int i = 0; i < 4; ++i) xr[i] = xs[i];
#pragma unroll
    for (int i = 0; i < 4; ++i) cr[i] = cs[i];
#pragma unroll
    for (int i = 0; i < 2; ++i)
      *(short8*)(xb + SWZ(sr*128 + sc0 + i*8, sr)) = pack8(xr[2*i], xr[2*i+1]);
#pragma unroll
    for (int i = 0; i < 2; ++i)
      *(short8*)(cb + SWZ(sr*128 + sc0 + i*8, sr)) = pack8(cr[2*i], cr[2*i+1]);
  }
  __syncthreads();

  const int sA = ((lane & 16) << 1) | (lane & 15);
  const int sB = sA + 16;
  const unsigned selp = (lane & 32) ? 0x07060302u : 0x05040100u;

  bf16x8 qB[2];
  float scl = __expf(fminf(logit_scale[h], 4.605170185988091f));
  {
    floatx4 aq[2][2] = {};
    for (int ks = 0; ks < 4; ++ks) {
      bf16x8 xf[2], wf[2];
#pragma unroll
      for (int n = 0; n < 2; ++n) {
        int tok = (2*s + n)*16 + lr;
        xf[n] = frag_bf(xb + SWZ(tok*128 + ks*32 + lg*8, tok));
      }
#pragma unroll
      for (int mc = 0; mc < 2; ++mc)
        wf[mc] = frag_bf(wq + (h*32 + mc*16 + lr)*DIM + ks*32 + lg*8);
#pragma unroll
      for (int mc = 0; mc < 2; ++mc)
#pragma unroll
        for (int n = 0; n < 2; ++n)
          aq[mc][n] = MFMA(wf[mc], xf[n], aq[mc][n]);
    }
    floatx4 qb4[2];
#pragma unroll
    for (int mc = 0; mc < 2; ++mc)
      qb4[mc] = *(const floatx4*)(q_b + h*32 + mc*16 + lg*4);
#pragma unroll
    for (int n = 0; n < 2; ++n) {
      float ss = 0.f;
#pragma unroll
      for (int mc = 0; mc < 2; ++mc)
#pragma unroll
        for (int i = 0; i < 4; ++i) {
          aq[mc][n][i] += qb4[mc][i];
          ss += aq[mc][n][i]*aq[mc][n][i];
        }
      ss += __shfl_xor(ss, 16, 64);
      ss += __shfl_xor(ss, 32, 64);
      float sc = scl / fmaxf(sqrtf(ss), 1e-12f);
#pragma unroll
      for (int mc = 0; mc < 2; ++mc)
#pragma unroll
        for (int i = 0; i < 4; ++i) aq[mc][n][i] *= sc;
      unsigned pq[4], w[8];
#pragma unroll
      for (int i = 0; i < 4; ++i) pq[i] = pk2(aq[0][n][i], aq[1][n][i]);
#pragma unroll
      for (int j = 0; j < 8; ++j) w[j] = __shfl(pq[j & 3], (j < 4) ? sA : sB, 64);
      uintx4 u;
#pragma unroll
      for (int t = 0; t < 4; ++t) u[t] = __builtin_amdgcn_perm(w[2*t+1], w[2*t], selp);
      qB[n] = __builtin_bit_cast(bf16x8, u);
    }
  }

  {
    floatx4 ak[2][2] = {};
    for (int ks = 0; ks < 4; ++ks) {
      bf16x8 cf[2], wkf[2];
#pragma unroll
      for (int r = 0; r < 2; ++r) {
        int tok = (2*s + r)*16 + lr;
        cf[r] = frag_bf(cb + SWZ(tok*128 + ks*32 + lg*8, tok));
      }
#pragma unroll
      for (int mc = 0; mc < 2; ++mc)
        wkf[mc] = frag_bf(wkv + (h*32 + mc*16 + lr)*DIM + ks*32 + lg*8);
#pragma unroll
      for (int mc = 0; mc < 2; ++mc)
#pragma unroll
        for (int n = 0; n < 2; ++n)
          ak[mc][n] = MFMA(wkf[mc], cf[n], ak[mc][n]);
    }
#pragma unroll
    for (int n = 0; n < 2; ++n) {
      float ss = 0.f;
#pragma unroll
      for (int mc = 0; mc < 2; ++mc)
#pragma unroll
        for (int i = 0; i < 4; ++i) ss += ak[mc][n][i]*ak[mc][n][i];
      ss += __shfl_xor(ss, 16, 64);
      ss += __shfl_xor(ss, 32, 64);
      float sc = 1.0f / fmaxf(sqrtf(ss), 1e-12f);
#pragma unroll
      for (int mc = 0; mc < 2; ++mc)
#pragma unroll
        for (int i = 0; i < 4; ++i) ak[mc][n][i] *= sc;
    }
#pragma unroll
    for (int mc = 0; mc < 2; ++mc)
#pragma unroll
      for (int n = 0; n < 2; ++n) {
        int tok = (2*s + n)*16 + lr;
        short4v t4;
#pragma unroll
        for (int i = 0; i < 4; ++i) t4[i] = bfbits(ak[mc][n][i]);
        *(short4v*)(knh + SWZ(tok*32 + mc*16 + lg*4, tok)) = t4;
      }
  }
  __syncthreads();

  {
    floatx4 av[2][2] = {};
    for (int ks = 0; ks < 4; ++ks) {
      bf16x8 cf[2], wvf[2];
#pragma unroll
      for (int r = 0; r < 2; ++r) {
        int tok = (2*s + r)*16 + lr;
        cf[r] = frag_bf(cb + SWZ(tok*128 + ks*32 + lg*8, tok));
      }
#pragma unroll
      for (int mc = 0; mc < 2; ++mc)
        wvf[mc] = frag_bf(wkv + (DIM + h*32 + mc*16 + lr)*DIM + ks*32 + lg*8);
#pragma unroll
      for (int mc = 0; mc < 2; ++mc)
#pragma unroll
        for (int n = 0; n < 2; ++n)
          av[mc][n] = MFMA(cf[mc], wvf[n], av[mc][n]);
    }
    float vb0 = v_b[h*32 + lr], vb1 = v_b[h*32 + 16 + lr];
#pragma unroll
    for (int m = 0; m < 2; ++m)
#pragma unroll
      for (int n = 0; n < 2; ++n) {
        int chG = h*32 + n*16 + lr;
        float vb = n ? vb1 : vb0;
        short4v t4;
#pragma unroll
        for (int i = 0; i < 4; ++i) t4[i] = bfbits(av[m][n][i] + vb);
        *(short4v*)(vT + SWZ(chG*64 + s*32 + m*16 + lg*4, chG)) = t4;
      }
  }
  __syncthreads();

  floatx4 st[4][2] = {};
#pragma unroll
  for (int mk = 0; mk < 4; ++mk) {
    int tok = mk*16 + lr;
    bf16x8 kf = frag_bf(knh + SWZ(tok*32 + lg*8, tok));
#pragma unroll
    for (int n = 0; n < 2; ++n)
      st[mk][n] = MFMA(kf, qB[n], st[mk][n]);
  }

  float rinv[2];
  {
    int wimg = b & 63;
#pragma unroll
    for (int n = 0; n < 2; ++n) {
      int qcol = (2*s + n)*16 + lr;
#pragma unroll
      for (int mk = 0; mk < 4; ++mk) {
        floatx4 b4 = ((const floatx4*)bias_p)[((h*4 + mk)*4 + (2*s + n))*64 + lane];
        floatx4 m4 = *(const floatx4*)(mask + ((size_t)wimg*64 + qcol)*64 + mk*16 + lg*4);
#pragma unroll
        for (int i = 0; i < 4; ++i) st[mk][n][i] += b4[i] + m4[i];
      }
      float mx = st[0][n][0];
#pragma unroll
      for (int mk = 0; mk < 4; ++mk)
#pragma unroll
        for (int i = 0; i < 4; ++i) mx = fmaxf(mx, st[mk][n][i]);
      mx = fmaxf(mx, __shfl_xor(mx, 16, 64));
      mx = fmaxf(mx, __shfl_xor(mx, 32, 64));
      float sum = 0.f;
#pragma unroll
      for (int mk = 0; mk < 4; ++mk)
#pragma unroll
        for (int i = 0; i < 4; ++i) {
          st[mk][n][i] = __expf(st[mk][n][i] - mx);
          sum += st[mk][n][i];
        }
      sum += __shfl_xor(sum, 16, 64);
      sum += __shfl_xor(sum, 32, 64);
      rinv[n] = 1.0f / sum;
    }
  }

  bf16x8 pB[2][2];
#pragma unroll
  for (int kk = 0; kk < 2; ++kk)
#pragma unroll
    for (int n = 0; n < 2; ++n) {
      unsigned pp[4], w[8];
#pragma unroll
      for (int i = 0; i < 4; ++i) pp[i] = pk2(st[2*kk][n][i], st[2*kk+1][n][i]);
#pragma unroll
      for (int j = 0; j < 8; ++j) w[j] = __shfl(pp[j & 3], (j < 4) ? sA : sB, 64);
      uintx4 u;
#pragma unroll
      for (int t = 0; t < 4; ++t) u[t] = __builtin_amdgcn_perm(w[2*t+1], w[2*t], selp);
      pB[kk][n] = __builtin_bit_cast(bf16x8, u);
    }
  floatx4 ot[2][2] = {};
#pragma unroll
  for (int kk = 0; kk < 2; ++kk) {
    bf16x8 vf[2];
#pragma unroll
    for (int mo = 0; mo < 2; ++mo) {
      int chG = h*32 + mo*16 + lr;
      vf[mo] = frag_bf(vT + SWZ(chG*64 + kk*32 + lg*8, chG));
    }
#pragma unroll
    for (int mo = 0; mo < 2; ++mo)
#pragma unroll
      for (int n = 0; n < 2; ++n)
        ot[mo][n] = MFMA(vf[mo], pB[kk][n], ot[mo][n]);
  }

#pragma unroll
  for (int mo = 0; mo < 2; ++mo)
#pragma unroll
    for (int n = 0; n < 2; ++n) {
      int tok = (2*s + n)*16 + lr;
      short4v t4;
#pragma unroll
      for (int i = 0; i < 4; ++i) t4[i] = bfbits(ot[mo][n][i] * rinv[n]);
      *(short4v*)(outp + SWZ(tok*128 + h*32 + mo*16 + lg*4, tok)) = t4;
    }
  __syncthreads();

  {
    floatx4 ap[2][2] = {};
    for (int ks = 0; ks < 4; ++ks) {
      bf16x8 of[2], wpf[2];
#pragma unroll
      for (int m = 0; m < 2; ++m) {
        int tok = s*32 + m*16 + lr;
        of[m] = frag_bf(outp + SWZ(tok*128 + ks*32 + lg*8, tok));
      }
#pragma unroll
      for (int n = 0; n < 2; ++n)
        wpf[n] = frag_bf(wproj + (h*32 + n*16 + lr)*DIM + ks*32 + lg*8);
#pragma unroll
      for (int m = 0; m < 2; ++m)
#pragma unroll
        for (int n = 0; n < 2; ++n)
          ap[m][n] = MFMA(of[m], wpf[n], ap[m][n]);
    }
    float pb0 = proj_b[h*32 + lr], pb1 = proj_b[h*32 + 16 + lr];
    float* op = out + (size_t)b * (NT*DIM);
#pragma unroll
    for (int m = 0; m < 2; ++m)
#pragma unroll
      for (int n = 0; n < 2; ++n) {
        float pb = n ? pb1 : pb0;
#pragma unroll
        for (int i = 0; i < 4; ++i)
          op[(s*32 + m*16 + lg*4 + i)*DIM + h*32 + n*16 + lr] = ap[m][n][i] + pb;
      }
  }
}

extern "C" void kernel_launch(void* const* d_in, const int* in_sizes, int n_in,
                              void* d_out, int out_size, void* d_ws, size_t ws_size,
                              hipStream_t stream) {
  const float* x     = (const float*)d_in[0];
  const float* ctx   = (const float*)d_in[1];
  const float* mask  = (const float*)d_in[2];
  const float* q_w   = (const float*)d_in[3];
  const float* q_b   = (const float*)d_in[4];
  const float* kv_w  = (const float*)d_in[5];
  const float* v_b   = (const float*)d_in[6];
  const float* ls    = (const float*)d_in[7];
  const float* w1    = (const float*)d_in[8];
  const float* b1    = (const float*)d_in[9];
  const float* w2    = (const float*)d_in[10];
  const float* pw    = (const float*)d_in[11];
  const float* pb    = (const float*)d_in[12];
  const float* table = (const float*)d_in[13];
  const int*   idx   = (const int*)d_in[14];

  float* bias_p = (float*)d_ws;                       // 64 KB
  short* wbf    = (short*)((char*)d_ws + 65536);      // 128 KB
  short* wq     = wbf;
  short* wkv    = wbf + 16384;
  short* wproj  = wbf + 49152;
  int B = in_sizes[0] / (NT * DIM);

  prep_kernel<<<17, 256, 0, stream>>>(table, w1, b1, w2, idx, q_w, kv_w, pw,
                                      bias_p, wbf);

  const size_t per_tensor = (size_t)B * 4 * 64 * 32;  // bf16 elems
  const size_t needed = 196608 + 3 * per_tensor * sizeof(short);
  if (ws_size >= needed) {
    short* qn = (short*)((char*)d_ws + 196608);
    short* kn = qn + per_tensor;
    short* vt = kn + per_tensor;
    qkv_kernel<<<B, 256, 0, stream>>>(x, ctx, wq, q_b, wkv, v_b, ls, qn, kn, vt);
    attn_proj_kernel<<<B, 256, 0, stream>>>(qn, kn, vt, mask, wproj, pb, bias_p,
                                            (float*)d_out);
  } else {
    fused_fallback_kernel<<<B, 512, 0, stream>>>(x, ctx, mask, wq, q_b, wkv, v_b,
                                                 ls, wproj, pb, bias_p, (float*)d_out);
  }
}